// Round 4
// baseline (485.683 us; speedup 1.0000x reference)
//
#include <hip/hip_runtime.h>
#include <hip/hip_bf16.h>
#include <cstdint>
#include <cstddef>

constexpr int C_  = 256;
constexpr int H_  = 224;
constexpr int W_  = 224;
constexpr int P_  = 49;
constexpr int M_  = 1024;
constexpr int HW_ = H_ * W_;

constexpr size_t IMG_ELEMS = (size_t)4 * C_ * H_ * W_;
constexpr size_t SCO_ELEMS = (size_t)4 * M_ * P_ * P_;
constexpr size_t OFF_SC  = IMG_ELEMS;
constexpr size_t OFF_COV = OFF_SC  + SCO_ELEMS;
constexpr size_t OFF_L   = OFF_COV + SCO_ELEMS;
constexpr size_t OFF_EC  = OFF_L   + SCO_ELEMS;

typedef __attribute__((ext_vector_type(8))) short short8;
typedef __attribute__((ext_vector_type(4))) float f32x4;

// LDS byte map (total 48,240 <= 53,333 -> 3 blocks/CU):
//   sA  : [0, 25088)        49 rows x 512B  bf16 A row-major, XOR-swizzled rows
//   Gb  : [25088, 31360)    49 rows x 128B  bf16 (G - u); Lb overlays after cov
//   Scb : [31360, 37632)    49 rows x 128B  bf16 Sc
//   sG  : [37632, 47432)    49 x 50 f32     G -> exp -> Sc (in place)
//   rowmax/u/w/T2 : 4 x 49 f32
// Overflow-read audit (MFMA frag rows 49..63): sA rows 49-63 -> Gb/Scb/sG
// (stale at G-time: NaN only in discarded D rows/cols; written-finite at Ec
// time where they multiply Lb's zero k-columns). Gb rows 49-63 -> Scb
// (finite). Scb rows 49-63 -> sG (f32 Sc reinterp: NaN possible -> only
// discarded q>=49 columns). All NaN paths end in never-stored elements.
constexpr int SA_OFF  = 0;
constexpr int GB_OFF  = 25088;
constexpr int SCB_OFF = 31360;
constexpr int SG_OFF  = 37632;
constexpr int RM_OFF  = 47432;
constexpr int U_OFF   = 47632;
constexpr int W_OFF   = 47832;
constexpr int T2_OFF  = 48032;
constexpr int SMEM_BYTES = 48240;

// Row-dependent 16B-unit XOR swizzle: balances banks for b128 row reads
// (lanes = rows) AND scalar column reads (k-group g enters via row bit 3).
__device__ __forceinline__ int srowswz(int r) { return ((r ^ (r >> 3)) & 7) << 4; }

__global__ __launch_bounds__(256, 3)
void psa_kernel(const float* __restrict__ x, const float* __restrict__ betap,
                float* __restrict__ out_img, float* __restrict__ out_sc,
                float* __restrict__ out_cov, float* __restrict__ out_l,
                float* __restrict__ out_ec)
{
    __shared__ __align__(16) unsigned char smem[SMEM_BYTES];
    float* sG     = (float*)(smem + SG_OFF);
    float* rowmax = (float*)(smem + RM_OFF);
    float* uArr   = (float*)(smem + U_OFF);
    float* wArr   = (float*)(smem + W_OFF);
    float* t2Arr  = (float*)(smem + T2_OFF);

    const int tid = threadIdx.x;
    const int bid = blockIdx.x;
    const int bm  = ((bid & 7) << 9) | (bid >> 3);   // XCD-bijective swizzle
    const int b   = bm >> 10;
    const int m   = bm & (M_ - 1);
    const int mh  = m >> 5;
    const int mw  = m & 31;
    const float beta = betap[0];
    const size_t xpatch = (((size_t)b * C_ * H_) + (size_t)mh * 7) * W_ + (size_t)mw * 7;

    const int wid = tid >> 6, lane = tid & 63, l15 = lane & 15, lh = lane >> 4;

    // ---- Phase 0: stage x -> sA (bf16, swizzled). thread = channel ----
    {
        const int c = tid;
        const float* src = x + xpatch + (size_t)c * HW_;
        #pragma unroll
        for (int i = 0; i < 7; ++i) {
            #pragma unroll
            for (int j = 0; j < 7; ++j) {
                const int p = i * 7 + j;
                *(__hip_bfloat16*)(smem + SA_OFF + p * 512 + ((2 * c) ^ srowswz(p))) =
                    __float2bfloat16(src[i * W_ + j]);
            }
        }
    }
    __syncthreads();

    // ---- Phase 1: G = A A^T (MFMA, K=256). wave wid -> rows 16wid..+15 ----
    {
        f32x4 acc[4] = {f32x4{0,0,0,0}, f32x4{0,0,0,0}, f32x4{0,0,0,0}, f32x4{0,0,0,0}};
        const int arow = 16 * wid + l15;
        #pragma unroll
        for (int kc = 0; kc < 8; ++kc) {
            const int cb = 64 * kc + 16 * lh;   // byte offset of this lane's k-octet
            const short8 af = *(const short8*)(smem + SA_OFF + arow * 512 + (cb ^ srowswz(arow)));
            #pragma unroll
            for (int t = 0; t < 4; ++t) {
                const int brow = 16 * t + l15;
                const short8 bf = *(const short8*)(smem + SA_OFF + brow * 512 + (cb ^ srowswz(brow)));
                acc[t] = __builtin_amdgcn_mfma_f32_16x16x32_bf16(af, bf, acc[t], 0, 0, 0);
            }
        }
        #pragma unroll
        for (int t = 0; t < 4; ++t) {
            const int q = 16 * t + l15;
            if (q <= 48) {
                #pragma unroll
                for (int r = 0; r < 4; ++r) {
                    const int p = 16 * wid + 4 * lh + r;
                    if (p <= 48) sG[p * 50 + q] = acc[t][r];
                }
            }
        }
    }
    __syncthreads();

    // ---- Phase 2: rowmax + u (= rowmean; G symmetric). 4 lanes/row ----
    if (tid < 196) {
        const int row = tid >> 2, s = tid & 3;
        const int qa = s * 13, qb = (qa + 13 < 49) ? qa + 13 : 49;
        float mx = -3.4e38f, sm = 0.f;
        for (int q = qa; q < qb; ++q) {
            const float v = sG[row * 50 + q];
            mx = fmaxf(mx, v); sm += v;
        }
        mx = fmaxf(mx, __shfl_xor(mx, 1));
        mx = fmaxf(mx, __shfl_xor(mx, 2));
        sm += __shfl_xor(sm, 1);
        sm += __shfl_xor(sm, 2);
        if (s == 0) { rowmax[row] = mx; uArr[row] = sm * (1.f / 49.f); }
    }
    __syncthreads();

    // ---- Phase 3: fused Gb = bf16(G - u) + in-place exp; zero pad cols ----
    for (int e = tid; e < 49 * 64; e += 256) {
        const int p = e >> 6, r = e & 63;
        if (r < 49) {
            const float gv = sG[p * 50 + r];
            *(__hip_bfloat16*)(smem + GB_OFF + p * 128 + ((2 * r) ^ srowswz(p))) =
                __float2bfloat16(gv - uArr[r]);
            sG[p * 50 + r] = __expf(gv - rowmax[p]);
        } else {
            *(short*)(smem + GB_OFF  + p * 128 + ((2 * r) ^ srowswz(p))) = 0;
            *(short*)(smem + SCB_OFF + p * 128 + ((2 * r) ^ srowswz(p))) = 0;
        }
    }
    __syncthreads();

    // ---- Phase 4: rowsum -> scale; write Sc (fp32 LDS + global + bf16 Scb) ----
    if (tid < 196) {
        const int row = tid >> 2, s = tid & 3;
        const int qa = s * 13, qb = (qa + 13 < 49) ? qa + 13 : 49;
        float sm = 0.f;
        for (int q = qa; q < qb; ++q) sm += sG[row * 50 + q];
        sm += __shfl_xor(sm, 1);
        sm += __shfl_xor(sm, 2);
        const float rinv = 1.f / sm;
        float* sc_g = out_sc + (size_t)bm * (P_ * P_) + row * 49;
        for (int q = qa; q < qb; ++q) {
            const float v = sG[row * 50 + q] * rinv;
            sG[row * 50 + q] = v;
            sc_g[q] = v;
            *(__hip_bfloat16*)(smem + SCB_OFF + row * 128 + ((2 * q) ^ srowswz(row))) =
                __float2bfloat16(v);
        }
    }
    __syncthreads();

    // ---- Phase 5a: w = colmean(Sc) ----
    if (tid < 196) {
        const int r = tid >> 2, s = tid & 3;
        const int pa = s * 13, pb = (pa + 13 < 49) ? pa + 13 : 49;
        float sm = 0.f;
        for (int p = pa; p < pb; ++p) sm += sG[p * 50 + r];
        sm += __shfl_xor(sm, 1);
        sm += __shfl_xor(sm, 2);
        if (s == 0) wArr[r] = sm * (1.f / 49.f);
    }
    __syncthreads();

    // ---- Phase 5b: T2[p] = sum_r Gb[p][r] * w[r] ----
    if (tid < 196) {
        const int p = tid >> 2, s = tid & 3;
        const int ra = s * 13, rb = (ra + 13 < 49) ? ra + 13 : 49;
        float sm = 0.f;
        for (int r = ra; r < rb; ++r) {
            const float gb = __bfloat162float(
                *(const __hip_bfloat16*)(smem + GB_OFF + p * 128 + ((2 * r) ^ srowswz(p))));
            sm += gb * wArr[r];
        }
        sm += __shfl_xor(sm, 1);
        sm += __shfl_xor(sm, 2);
        if (s == 0) t2Arr[p] = sm;
    }
    __syncthreads();

    // ---- Phase 6: cov MFMA: D = Gb . Scb^T (K=64) ----
    f32x4 cacc[4] = {f32x4{0,0,0,0}, f32x4{0,0,0,0}, f32x4{0,0,0,0}, f32x4{0,0,0,0}};
    {
        const int arow = 16 * wid + l15;
        #pragma unroll
        for (int kc = 0; kc < 2; ++kc) {
            const int cb = 64 * kc + 16 * lh;
            const short8 af = *(const short8*)(smem + GB_OFF + arow * 128 + (cb ^ srowswz(arow)));
            #pragma unroll
            for (int t = 0; t < 4; ++t) {
                const int brow = 16 * t + l15;
                const short8 bf = *(const short8*)(smem + SCB_OFF + brow * 128 + (cb ^ srowswz(brow)));
                cacc[t] = __builtin_amdgcn_mfma_f32_16x16x32_bf16(af, bf, cacc[t], 0, 0, 0);
            }
        }
    }
    __syncthreads();   // cov reads done before Lb overlays Gb

    // ---- Phase 7: cov epilogue: cv = (acc - T2[p])/49; L = Sc + cv; Lb ----
    {
        float* cov_g = out_cov + (size_t)bm * (P_ * P_);
        float* l_g   = out_l   + (size_t)bm * (P_ * P_);
        #pragma unroll
        for (int t = 0; t < 4; ++t) {
            const int q = 16 * t + l15;
            #pragma unroll
            for (int r = 0; r < 4; ++r) {
                const int p = 16 * wid + 4 * lh + r;
                if (p <= 48 && q <= 48) {
                    const float cv = (cacc[t][r] - t2Arr[p]) * (1.f / 49.f);
                    const float lv = sG[p * 50 + q] + cv;
                    cov_g[p * 49 + q] = cv;
                    l_g  [p * 49 + q] = lv;
                    *(__hip_bfloat16*)(smem + GB_OFF + p * 128 + ((2 * q) ^ srowswz(p))) =
                        __float2bfloat16(lv);   // Lb; cols 49..63 keep Gb zeros
                }
            }
        }
    }
    __syncthreads();

    // ---- Phase 8: Ec = L . A (D[p][c]); wave wid -> c in [64wid, 64wid+64) ----
    {
        f32x4 acc[4][4];   // [nt][mt]
        #pragma unroll
        for (int i = 0; i < 4; ++i)
            #pragma unroll
            for (int j2 = 0; j2 < 4; ++j2) acc[i][j2] = f32x4{0, 0, 0, 0};

        #pragma unroll
        for (int kc = 0; kc < 2; ++kc) {
            const int cb = 64 * kc + 16 * lh;
            short8 af[4];
            #pragma unroll
            for (int mt = 0; mt < 4; ++mt) {
                const int prow = 16 * mt + l15;
                af[mt] = *(const short8*)(smem + GB_OFF + prow * 128 + (cb ^ srowswz(prow)));
            }
            #pragma unroll
            for (int nt = 0; nt < 4; ++nt) {
                const int c = 64 * wid + 16 * nt + l15;
                short8 bf;
                #pragma unroll
                for (int j = 0; j < 8; ++j) {
                    const int q = 32 * kc + 8 * lh + j;   // col read of A via swizzle
                    bf[j] = *(const short*)(smem + SA_OFF + q * 512 + ((2 * c) ^ srowswz(q)));
                }
                #pragma unroll
                for (int mt = 0; mt < 4; ++mt)
                    acc[nt][mt] = __builtin_amdgcn_mfma_f32_16x16x32_bf16(af[mt], bf, acc[nt][mt], 0, 0, 0);
            }
        }

        // Epilogue: D[p][c]; xv from sA (bf16) — no global x re-read
        #pragma unroll
        for (int nt = 0; nt < 4; ++nt) {
            const int c = 64 * wid + 16 * nt + l15;
            #pragma unroll
            for (int mt = 0; mt < 4; ++mt) {
                #pragma unroll
                for (int r = 0; r < 4; ++r) {
                    const int p = 16 * mt + 4 * lh + r;
                    if (p > 48) continue;
                    const int i = p / 7, j = p - 7 * (p / 7);
                    const size_t g = xpatch + (size_t)c * HW_ + (size_t)i * W_ + j;
                    const float ec = acc[nt][mt][r];
                    const float xv = __bfloat162float(
                        *(const __hip_bfloat16*)(smem + SA_OFF + p * 512 + ((2 * c) ^ srowswz(p))));
                    out_ec [g] = ec;
                    out_img[g] = xv * fmaf(beta, ec, xv);
                }
            }
        }
    }
}

extern "C" void kernel_launch(void* const* d_in, const int* in_sizes, int n_in,
                              void* d_out, int out_size, void* d_ws, size_t ws_size,
                              hipStream_t stream) {
    const float* x    = (const float*)d_in[0];
    const float* beta = (const float*)d_in[1];
    float* out = (float*)d_out;
    psa_kernel<<<dim3(4 * M_), dim3(256), 0, stream>>>(
        x, beta,
        out,
        out + OFF_SC,
        out + OFF_COV,
        out + OFF_L,
        out + OFF_EC);
}

// Round 5
// 444.446 us; speedup vs baseline: 1.0928x; 1.0928x over previous
//
#include <hip/hip_runtime.h>
#include <hip/hip_bf16.h>
#include <cstdint>
#include <cstddef>

constexpr int C_  = 256;
constexpr int H_  = 224;
constexpr int W_  = 224;
constexpr int P_  = 49;
constexpr int M_  = 1024;
constexpr int HW_ = H_ * W_;

constexpr size_t IMG_ELEMS = (size_t)4 * C_ * H_ * W_;
constexpr size_t SCO_ELEMS = (size_t)4 * M_ * P_ * P_;
constexpr size_t OFF_SC  = IMG_ELEMS;
constexpr size_t OFF_COV = OFF_SC  + SCO_ELEMS;
constexpr size_t OFF_L   = OFF_COV + SCO_ELEMS;
constexpr size_t OFF_EC  = OFF_L   + SCO_ELEMS;

typedef __attribute__((ext_vector_type(8))) short short8;
typedef __attribute__((ext_vector_type(4))) float f32x4;

// LDS byte map (total 48,240 -> 3 blocks/CU):
//   sA  : [0, 25088)        49 rows x 512B  bf16 A row-major, XOR-swizzled rows
//   Gb  : [25088, 31360)    49 rows x 128B  bf16 (G - u); Lb overlays after cov
//   Scb : [31360, 37632)    49 rows x 128B  bf16 Sc
//   sG  : [37632, 47432)    49 x 50 f32     G -> exp -> Sc (in place)
//   rowmax/u/w/T2 : 4 x 49 f32
// Out-of-range MFMA fragment reads (rows/q 49..63) all end in discarded D
// rows/cols or multiply Lb's zero k-columns; regions read are finite bf16.
constexpr int SA_OFF  = 0;
constexpr int GB_OFF  = 25088;
constexpr int SCB_OFF = 31360;
constexpr int SG_OFF  = 37632;
constexpr int RM_OFF  = 47432;
constexpr int U_OFF   = 47632;
constexpr int W_OFF   = 47832;
constexpr int T2_OFF  = 48032;
constexpr int SMEM_BYTES = 48240;

// Row-dependent 16B-unit XOR swizzle: balances banks for b128 row reads
// (lanes = rows) AND scalar column reads (k-group enters via row bit 3).
__device__ __forceinline__ int srowswz(int r) { return ((r ^ (r >> 3)) & 7) << 4; }

__global__ __launch_bounds__(256, 3)
void psa_kernel(const float* __restrict__ x, const float* __restrict__ betap,
                float* __restrict__ out_img, float* __restrict__ out_sc,
                float* __restrict__ out_cov, float* __restrict__ out_l,
                float* __restrict__ out_ec)
{
    __shared__ __align__(16) unsigned char smem[SMEM_BYTES];
    float* sG     = (float*)(smem + SG_OFF);
    float* rowmax = (float*)(smem + RM_OFF);
    float* uArr   = (float*)(smem + U_OFF);
    float* wArr   = (float*)(smem + W_OFF);
    float* t2Arr  = (float*)(smem + T2_OFF);

    const int tid = threadIdx.x;
    const int bid = blockIdx.x;
    const int bm  = ((bid & 7) << 9) | (bid >> 3);   // XCD-bijective swizzle
    const int b   = bm >> 10;
    const int m   = bm & (M_ - 1);
    const int mh  = m >> 5;
    const int mw  = m & 31;
    const float beta = betap[0];
    const size_t xpatch = (((size_t)b * C_ * H_) + (size_t)mh * 7) * W_ + (size_t)mw * 7;

    const int wid = tid >> 6, lane = tid & 63, l15 = lane & 15, lh = lane >> 4;

    // ---- Phase 0: stage x -> sA (bf16, swizzled). thread = channel ----
    {
        const int c = tid;
        const float* src = x + xpatch + (size_t)c * HW_;
        #pragma unroll
        for (int i = 0; i < 7; ++i) {
            #pragma unroll
            for (int j = 0; j < 7; ++j) {
                const int p = i * 7 + j;
                *(__hip_bfloat16*)(smem + SA_OFF + p * 512 + ((2 * c) ^ srowswz(p))) =
                    __float2bfloat16(src[i * W_ + j]);
            }
        }
    }
    __syncthreads();

    // ---- Phase 1: G = A A^T (MFMA, K=256). wave wid -> rows 16wid..+15 ----
    {
        f32x4 acc[4] = {f32x4{0,0,0,0}, f32x4{0,0,0,0}, f32x4{0,0,0,0}, f32x4{0,0,0,0}};
        const int arow = 16 * wid + l15;
        #pragma unroll
        for (int kc = 0; kc < 8; ++kc) {
            const int cb = 64 * kc + 16 * lh;   // byte offset of this lane's k-octet
            const short8 af = *(const short8*)(smem + SA_OFF + arow * 512 + (cb ^ srowswz(arow)));
            #pragma unroll
            for (int t = 0; t < 4; ++t) {
                const int brow = 16 * t + l15;
                const short8 bf = *(const short8*)(smem + SA_OFF + brow * 512 + (cb ^ srowswz(brow)));
                acc[t] = __builtin_amdgcn_mfma_f32_16x16x32_bf16(af, bf, acc[t], 0, 0, 0);
            }
        }
        #pragma unroll
        for (int t = 0; t < 4; ++t) {
            const int q = 16 * t + l15;
            if (q <= 48) {
                #pragma unroll
                for (int r = 0; r < 4; ++r) {
                    const int p = 16 * wid + 4 * lh + r;
                    if (p <= 48) sG[p * 50 + q] = acc[t][r];
                }
            }
        }
    }
    __syncthreads();

    // ---- Phase 2: rowmax + u (= rowmean; G symmetric). 4 lanes/row ----
    if (tid < 196) {
        const int row = tid >> 2, s = tid & 3;
        const int qa = s * 13, qb = (qa + 13 < 49) ? qa + 13 : 49;
        float mx = -3.4e38f, sm = 0.f;
        for (int q = qa; q < qb; ++q) {
            const float v = sG[row * 50 + q];
            mx = fmaxf(mx, v); sm += v;
        }
        mx = fmaxf(mx, __shfl_xor(mx, 1));
        mx = fmaxf(mx, __shfl_xor(mx, 2));
        sm += __shfl_xor(sm, 1);
        sm += __shfl_xor(sm, 2);
        if (s == 0) { rowmax[row] = mx; uArr[row] = sm * (1.f / 49.f); }
    }
    __syncthreads();

    // ---- Phase 3: fused Gb = bf16(G - u) + in-place exp; zero pad cols ----
    for (int e = tid; e < 49 * 64; e += 256) {
        const int p = e >> 6, r = e & 63;
        if (r < 49) {
            const float gv = sG[p * 50 + r];
            *(__hip_bfloat16*)(smem + GB_OFF + p * 128 + ((2 * r) ^ srowswz(p))) =
                __float2bfloat16(gv - uArr[r]);
            sG[p * 50 + r] = __expf(gv - rowmax[p]);
        } else {
            *(short*)(smem + GB_OFF  + p * 128 + ((2 * r) ^ srowswz(p))) = 0;
            *(short*)(smem + SCB_OFF + p * 128 + ((2 * r) ^ srowswz(p))) = 0;
        }
    }
    __syncthreads();

    // ---- Phase 4: rowsum -> scale; write Sc (fp32 LDS + global + bf16 Scb) ----
    if (tid < 196) {
        const int row = tid >> 2, s = tid & 3;
        const int qa = s * 13, qb = (qa + 13 < 49) ? qa + 13 : 49;
        float sm = 0.f;
        for (int q = qa; q < qb; ++q) sm += sG[row * 50 + q];
        sm += __shfl_xor(sm, 1);
        sm += __shfl_xor(sm, 2);
        const float rinv = 1.f / sm;
        float* sc_g = out_sc + (size_t)bm * (P_ * P_) + row * 49;
        for (int q = qa; q < qb; ++q) {
            const float v = sG[row * 50 + q] * rinv;
            sG[row * 50 + q] = v;
            sc_g[q] = v;
            *(__hip_bfloat16*)(smem + SCB_OFF + row * 128 + ((2 * q) ^ srowswz(row))) =
                __float2bfloat16(v);
        }
    }
    __syncthreads();

    // ---- Phase 5a: w = colmean(Sc) ----
    if (tid < 196) {
        const int r = tid >> 2, s = tid & 3;
        const int pa = s * 13, pb = (pa + 13 < 49) ? pa + 13 : 49;
        float sm = 0.f;
        for (int p = pa; p < pb; ++p) sm += sG[p * 50 + r];
        sm += __shfl_xor(sm, 1);
        sm += __shfl_xor(sm, 2);
        if (s == 0) wArr[r] = sm * (1.f / 49.f);
    }
    __syncthreads();

    // ---- Phase 5b: T2[p] = sum_r Gb[p][r] * w[r] ----
    if (tid < 196) {
        const int p = tid >> 2, s = tid & 3;
        const int ra = s * 13, rb = (ra + 13 < 49) ? ra + 13 : 49;
        float sm = 0.f;
        for (int r = ra; r < rb; ++r) {
            const float gb = __bfloat162float(
                *(const __hip_bfloat16*)(smem + GB_OFF + p * 128 + ((2 * r) ^ srowswz(p))));
            sm += gb * wArr[r];
        }
        sm += __shfl_xor(sm, 1);
        sm += __shfl_xor(sm, 2);
        if (s == 0) t2Arr[p] = sm;
    }
    __syncthreads();

    // ---- Phase 6: cov MFMA: D = Gb . Scb^T (K=64) ----
    f32x4 cacc[4] = {f32x4{0,0,0,0}, f32x4{0,0,0,0}, f32x4{0,0,0,0}, f32x4{0,0,0,0}};
    {
        const int arow = 16 * wid + l15;
        #pragma unroll
        for (int kc = 0; kc < 2; ++kc) {
            const int cb = 64 * kc + 16 * lh;
            const short8 af = *(const short8*)(smem + GB_OFF + arow * 128 + (cb ^ srowswz(arow)));
            #pragma unroll
            for (int t = 0; t < 4; ++t) {
                const int brow = 16 * t + l15;
                const short8 bf = *(const short8*)(smem + SCB_OFF + brow * 128 + (cb ^ srowswz(brow)));
                cacc[t] = __builtin_amdgcn_mfma_f32_16x16x32_bf16(af, bf, cacc[t], 0, 0, 0);
            }
        }
    }
    __syncthreads();   // cov reads done before Lb overlays Gb

    // ---- Phase 7: cov epilogue: cv = (acc - T2[p])/49; L = Sc + cv; Lb ----
    {
        float* cov_g = out_cov + (size_t)bm * (P_ * P_);
        float* l_g   = out_l   + (size_t)bm * (P_ * P_);
        #pragma unroll
        for (int t = 0; t < 4; ++t) {
            const int q = 16 * t + l15;
            #pragma unroll
            for (int r = 0; r < 4; ++r) {
                const int p = 16 * wid + 4 * lh + r;
                if (p <= 48 && q <= 48) {
                    const float cv = (cacc[t][r] - t2Arr[p]) * (1.f / 49.f);
                    const float lv = sG[p * 50 + q] + cv;
                    cov_g[p * 49 + q] = cv;
                    l_g  [p * 49 + q] = lv;
                    *(__hip_bfloat16*)(smem + GB_OFF + p * 128 + ((2 * q) ^ srowswz(p))) =
                        __float2bfloat16(lv);   // Lb; cols 49..63 keep Gb zeros
                }
            }
        }
    }
    __syncthreads();

    // ---- Phase 8: Ec^T = A^T . L^T (D[c][p]); wave wid -> c in [64wid, +64) ----
    // Lane dim = token p (coalesced stores); register dim = channel.
    {
        f32x4 acc[4][4];   // [ct][pt]
        #pragma unroll
        for (int i = 0; i < 4; ++i)
            #pragma unroll
            for (int j2 = 0; j2 < 4; ++j2) acc[i][j2] = f32x4{0, 0, 0, 0};

        #pragma unroll
        for (int kc = 0; kc < 2; ++kc) {
            const int cb = 64 * kc + 16 * lh;
            // B fragments: L^T — read Lb rows (= D cols p) at k-octet
            short8 bf[4];
            #pragma unroll
            for (int pt = 0; pt < 4; ++pt) {
                const int brow = 16 * pt + l15;
                bf[pt] = *(const short8*)(smem + GB_OFF + brow * 128 + (cb ^ srowswz(brow)));
            }
            // A fragments: A^T rows = channels; scalar column reads of sA
            #pragma unroll
            for (int ct = 0; ct < 4; ++ct) {
                const int c = 64 * wid + 16 * ct + l15;
                short8 af;
                #pragma unroll
                for (int j = 0; j < 8; ++j) {
                    const int q = 32 * kc + 8 * lh + j;
                    af[j] = *(const short*)(smem + SA_OFF + q * 512 + ((2 * c) ^ srowswz(q)));
                }
                #pragma unroll
                for (int pt = 0; pt < 4; ++pt)
                    acc[ct][pt] = __builtin_amdgcn_mfma_f32_16x16x32_bf16(af, bf[pt], acc[ct][pt], 0, 0, 0);
            }
        }

        // Epilogue: D[c][p]; lane holds p = 16pt + l15 (spatial, coalesced),
        // regs c = 64wid + 16ct + 4lh + r. xv from sA (bf16) — no global read.
        #pragma unroll
        for (int pt = 0; pt < 4; ++pt) {
            const int p = 16 * pt + l15;
            if (p > 48) continue;
            const int i = p / 7, j = p - 7 * (p / 7);
            const size_t base = xpatch + (size_t)i * W_ + j;
            #pragma unroll
            for (int ct = 0; ct < 4; ++ct) {
                #pragma unroll
                for (int r = 0; r < 4; ++r) {
                    const int c = 64 * wid + 16 * ct + 4 * lh + r;
                    const size_t g = base + (size_t)c * HW_;
                    const float ec = acc[ct][pt][r];
                    const float xv = __bfloat162float(
                        *(const __hip_bfloat16*)(smem + SA_OFF + p * 512 + ((2 * c) ^ srowswz(p))));
                    out_ec [g] = ec;
                    out_img[g] = xv * fmaf(beta, ec, xv);
                }
            }
        }
    }
}

extern "C" void kernel_launch(void* const* d_in, const int* in_sizes, int n_in,
                              void* d_out, int out_size, void* d_ws, size_t ws_size,
                              hipStream_t stream) {
    const float* x    = (const float*)d_in[0];
    const float* beta = (const float*)d_in[1];
    float* out = (float*)d_out;
    psa_kernel<<<dim3(4 * M_), dim3(256), 0, stream>>>(
        x, beta,
        out,
        out + OFF_SC,
        out + OFF_COV,
        out + OFF_L,
        out + OFF_EC);
}